// Round 1
// baseline (353.159 us; speedup 1.0000x reference)
//
#include <hip/hip_runtime.h>
#include <hip/hip_bf16.h>
#include <math.h>

#define DM   1024
#define SEQ  2048
#define NBAT 2
#define NH   16
#define MTOT 4096   // NBAT*SEQ

typedef __attribute__((ext_vector_type(8))) short short8;
typedef __attribute__((ext_vector_type(4))) float f32x4;

__device__ __forceinline__ unsigned short f2bf(float f) {
  unsigned int u = __float_as_uint(f);
  u += 0x7fff + ((u >> 16) & 1);   // RNE
  return (unsigned short)(u >> 16);
}

#define GLDS16(g, l)                                                            \
  __builtin_amdgcn_global_load_lds((const __attribute__((address_space(1))) void*)(g), \
                                   (__attribute__((address_space(3))) void*)(l), 16, 0, 0)

// ---------------- fp32 -> bf16 convert (elementwise, vectorized) -------------
__global__ __launch_bounds__(256) void cvt_bf16(const float* __restrict__ src,
                                                unsigned short* __restrict__ dst) {
  int i = (blockIdx.x * 256 + threadIdx.x) * 8;
  f32x4 a = *(const f32x4*)(src + i);
  f32x4 b = *(const f32x4*)(src + i + 4);
  short8 o;
  o[0] = (short)f2bf(a[0]); o[1] = (short)f2bf(a[1]);
  o[2] = (short)f2bf(a[2]); o[3] = (short)f2bf(a[3]);
  o[4] = (short)f2bf(b[0]); o[5] = (short)f2bf(b[1]);
  o[6] = (short)f2bf(b[2]); o[7] = (short)f2bf(b[3]);
  *(short8*)(dst + i) = o;
}

// ---------------- weight transpose + convert: W[K][N] -> Wt[N][K] bf16 -------
__global__ __launch_bounds__(256) void transpose_w(const float* __restrict__ W,
                                                   unsigned short* __restrict__ Wt) {
  __shared__ float tile[32][33];
  int bx = blockIdx.x * 32;  // n
  int by = blockIdx.y * 32;  // k
  int tx = threadIdx.x, ty = threadIdx.y; // 32 x 8
#pragma unroll
  for (int i = 0; i < 4; ++i)
    tile[ty + i * 8][tx] = W[(size_t)(by + ty + i * 8) * DM + bx + tx];
  __syncthreads();
#pragma unroll
  for (int i = 0; i < 4; ++i)
    Wt[(size_t)(bx + ty + i * 8) * DM + by + tx] = f2bf(tile[tx][ty + i * 8]);
}

// ---------------- bf16 GEMM: out = X[M,K] @ W[K,N] + bias --------------------
// Wt is W transposed: Wt[n][k].  mode 0: bf16 row-major out
//                               mode 1: Vt[b,h,d,s] transposed bf16 out
//                               mode 2: fp32 row-major out
__global__ __launch_bounds__(256) void gemm_bf16(const unsigned short* __restrict__ X,
                                                 const unsigned short* __restrict__ Wt,
                                                 const float* __restrict__ bias,
                                                 void* __restrict__ out, int mode) {
  __shared__ unsigned short As[128 * 32];
  __shared__ unsigned short Bs[128 * 32];
  const int t = threadIdx.x, l = t & 63, w = t >> 6;
  const int wr = w >> 1, wc = w & 1;
  const int fr = l & 15, fg = l >> 4;
  const int mb = blockIdx.x * 128, nb = blockIdx.y * 128;

  f32x4 acc[4][4] = {};

  const int srow = l >> 2;          // 0..15 within wave
  const int scol = (l & 3) * 8;     // 0,8,16,24

  for (int kt = 0; kt < DM; kt += 32) {
#pragma unroll
    for (int i = 0; i < 2; ++i) {
      int row = i * 64 + w * 16 + srow;
      GLDS16(X  + (size_t)(mb + row) * DM + kt + scol, &As[i * 2048 + w * 512]);
      GLDS16(Wt + (size_t)(nb + row) * DM + kt + scol, &Bs[i * 2048 + w * 512]);
    }
    __syncthreads();
    short8 af[4], bf[4];
#pragma unroll
    for (int mt = 0; mt < 4; ++mt)
      af[mt] = *(const short8*)&As[(wr * 64 + mt * 16 + fr) * 32 + fg * 8];
#pragma unroll
    for (int nt = 0; nt < 4; ++nt)
      bf[nt] = *(const short8*)&Bs[(wc * 64 + nt * 16 + fr) * 32 + fg * 8];
#pragma unroll
    for (int mt = 0; mt < 4; ++mt)
#pragma unroll
      for (int nt = 0; nt < 4; ++nt)
        acc[mt][nt] = __builtin_amdgcn_mfma_f32_16x16x32_bf16(af[mt], bf[nt], acc[mt][nt], 0, 0, 0);
    __syncthreads();
  }

#pragma unroll
  for (int nt = 0; nt < 4; ++nt) {
    int n = nb + wc * 64 + nt * 16 + fr;
    float bn = bias[n];
#pragma unroll
    for (int mt = 0; mt < 4; ++mt) {
#pragma unroll
      for (int r = 0; r < 4; ++r) {
        int m = mb + wr * 64 + mt * 16 + fg * 4 + r;
        float v = acc[mt][nt][r] + bn;
        if (mode == 0) {
          ((unsigned short*)out)[(size_t)m * DM + n] = f2bf(v);
        } else if (mode == 1) {
          int b = m >> 11, s = m & 2047;
          int h = n >> 6, d = n & 63;
          ((unsigned short*)out)[(((size_t)(b * NH + h) * 64 + d) * SEQ) + s] = f2bf(v);
        } else {
          ((float*)out)[(size_t)m * DM + n] = v;
        }
      }
    }
  }
}

// ---------------- flash attention ------------------------------------------
// Qh,Kh: bf16 [NBAT*SEQ][DM] (head h at cols h*64..h*64+63)
// Vt   : bf16 [NBAT*NH][64][SEQ]
// Oh   : bf16 [NBAT*SEQ][DM]
#define KVPAD 72
__global__ __launch_bounds__(256) void attn_fwd(const unsigned short* __restrict__ Qh,
                                                const unsigned short* __restrict__ Kh,
                                                const unsigned short* __restrict__ Vt,
                                                unsigned short* __restrict__ Oh) {
  __shared__ unsigned short Ks[64 * KVPAD];
  __shared__ unsigned short Vs[64 * KVPAD];
  __shared__ unsigned short Ps[4][16 * KVPAD];

  const int t = threadIdx.x, l = t & 63, w = t >> 6;
  const int fr = l & 15, fg = l >> 4;
  const int q0 = blockIdx.x * 64;
  const int bh = blockIdx.y;                 // b*NH + h
  const int b = bh >> 4, h = bh & 15;

  const unsigned short* Qp = Qh + (size_t)b * SEQ * DM + h * 64;
  const unsigned short* Kp = Kh + (size_t)b * SEQ * DM + h * 64;
  const unsigned short* Vp = Vt + (size_t)bh * 64 * SEQ;

  // Q fragments for this wave's 16 rows (kept in registers)
  const int qrow = q0 + w * 16 + fr;
  short8 qf0 = *(const short8*)(Qp + (size_t)qrow * DM + fg * 8);
  short8 qf1 = *(const short8*)(Qp + (size_t)qrow * DM + 32 + fg * 8);

  float m_run[4] = {-INFINITY, -INFINITY, -INFINITY, -INFINITY};
  float l_run[4] = {0.f, 0.f, 0.f, 0.f};
  f32x4 oacc[4] = {};

  const int srow = t >> 3;        // 0..31
  const int sseg = (t & 7) * 8;   // 0..56

  for (int kv = 0; kv < SEQ; kv += 64) {
#pragma unroll
    for (int i = 0; i < 2; ++i) {
      int row = i * 32 + srow;
      *(short8*)&Ks[row * KVPAD + sseg] = *(const short8*)(Kp + (size_t)(kv + row) * DM + sseg);
      *(short8*)&Vs[row * KVPAD + sseg] = *(const short8*)(Vp + (size_t)row * SEQ + kv + sseg);
    }
    __syncthreads();

    // S = (Q @ K^T) * 0.125
    f32x4 sf[4];
#pragma unroll
    for (int nt = 0; nt < 4; ++nt) {
      short8 kf0 = *(const short8*)&Ks[(nt * 16 + fr) * KVPAD + fg * 8];
      short8 kf1 = *(const short8*)&Ks[(nt * 16 + fr) * KVPAD + 32 + fg * 8];
      f32x4 a = {};
      a = __builtin_amdgcn_mfma_f32_16x16x32_bf16(qf0, kf0, a, 0, 0, 0);
      a = __builtin_amdgcn_mfma_f32_16x16x32_bf16(qf1, kf1, a, 0, 0, 0);
#pragma unroll
      for (int r = 0; r < 4; ++r) a[r] *= 0.125f;
      sf[nt] = a;
    }

    // online softmax: row stats live at (lane group fg, reg r) = row fg*4+r
    float mx[4], al[4], rs[4];
#pragma unroll
    for (int r = 0; r < 4; ++r)
      mx[r] = fmaxf(fmaxf(sf[0][r], sf[1][r]), fmaxf(sf[2][r], sf[3][r]));
#pragma unroll
    for (int off = 1; off <= 8; off <<= 1)
#pragma unroll
      for (int r = 0; r < 4; ++r) mx[r] = fmaxf(mx[r], __shfl_xor(mx[r], off, 64));
#pragma unroll
    for (int r = 0; r < 4; ++r) {
      float nm = fmaxf(m_run[r], mx[r]);
      al[r] = __expf(m_run[r] - nm);
      m_run[r] = nm;
      rs[r] = 0.f;
    }
#pragma unroll
    for (int nt = 0; nt < 4; ++nt)
#pragma unroll
      for (int r = 0; r < 4; ++r) {
        float p = __expf(sf[nt][r] - m_run[r]);
        sf[nt][r] = p;
        rs[r] += p;
      }
#pragma unroll
    for (int off = 1; off <= 8; off <<= 1)
#pragma unroll
      for (int r = 0; r < 4; ++r) rs[r] += __shfl_xor(rs[r], off, 64);
#pragma unroll
    for (int r = 0; r < 4; ++r) l_run[r] = l_run[r] * al[r] + rs[r];
#pragma unroll
    for (int dt = 0; dt < 4; ++dt)
#pragma unroll
      for (int r = 0; r < 4; ++r) oacc[dt][r] *= al[r];

    // P -> bf16 -> per-wave LDS (A-fragment layout round-trip)
#pragma unroll
    for (int nt = 0; nt < 4; ++nt)
#pragma unroll
      for (int r = 0; r < 4; ++r)
        Ps[w][(fg * 4 + r) * KVPAD + nt * 16 + fr] = f2bf(sf[nt][r]);

    short8 pf0 = *(const short8*)&Ps[w][fr * KVPAD + fg * 8];
    short8 pf1 = *(const short8*)&Ps[w][fr * KVPAD + 32 + fg * 8];
#pragma unroll
    for (int dt = 0; dt < 4; ++dt) {
      short8 vf0 = *(const short8*)&Vs[(dt * 16 + fr) * KVPAD + fg * 8];
      short8 vf1 = *(const short8*)&Vs[(dt * 16 + fr) * KVPAD + 32 + fg * 8];
      oacc[dt] = __builtin_amdgcn_mfma_f32_16x16x32_bf16(pf0, vf0, oacc[dt], 0, 0, 0);
      oacc[dt] = __builtin_amdgcn_mfma_f32_16x16x32_bf16(pf1, vf1, oacc[dt], 0, 0, 0);
    }
    __syncthreads();
  }

#pragma unroll
  for (int dt = 0; dt < 4; ++dt)
#pragma unroll
    for (int r = 0; r < 4; ++r) {
      int row = b * SEQ + q0 + w * 16 + fg * 4 + r;
      float v = oacc[dt][r] / l_run[r];
      Oh[(size_t)row * DM + h * 64 + dt * 16 + fr] = f2bf(v);
    }
}

// ---------------------------------------------------------------------------
extern "C" void kernel_launch(void* const* d_in, const int* in_sizes, int n_in,
                              void* d_out, int out_size, void* d_ws, size_t ws_size,
                              hipStream_t stream) {
  const float* v  = (const float*)d_in[0];
  const float* k  = (const float*)d_in[1];
  const float* q  = (const float*)d_in[2];
  const float* wq = (const float*)d_in[3];
  const float* bq = (const float*)d_in[4];
  const float* wk = (const float*)d_in[5];
  const float* bk = (const float*)d_in[6];
  const float* wv = (const float*)d_in[7];
  const float* bv = (const float*)d_in[8];
  const float* wo = (const float*)d_in[9];
  const float* bo = (const float*)d_in[10];

  char* ws = (char*)d_ws;
  const size_t MB = 1u << 20;
  unsigned short* qb  = (unsigned short*)(ws + 0 * MB);
  unsigned short* kb  = (unsigned short*)(ws + 8 * MB);
  unsigned short* vb  = (unsigned short*)(ws + 16 * MB);
  unsigned short* wqt = (unsigned short*)(ws + 24 * MB);
  unsigned short* wkt = (unsigned short*)(ws + 26 * MB);
  unsigned short* wvt = (unsigned short*)(ws + 28 * MB);
  unsigned short* wot = (unsigned short*)(ws + 30 * MB);
  unsigned short* Qh  = (unsigned short*)(ws + 32 * MB);
  unsigned short* Kh  = (unsigned short*)(ws + 40 * MB);
  unsigned short* Vt  = (unsigned short*)(ws + 48 * MB);
  unsigned short* AO  = (unsigned short*)(ws + 56 * MB);

  // fp32 -> bf16 activations
  cvt_bf16<<<2048, 256, 0, stream>>>(q, qb);
  cvt_bf16<<<2048, 256, 0, stream>>>(k, kb);
  cvt_bf16<<<2048, 256, 0, stream>>>(v, vb);

  // weights: transpose + convert
  dim3 tg(32, 32), tb(32, 8);
  transpose_w<<<tg, tb, 0, stream>>>(wq, wqt);
  transpose_w<<<tg, tb, 0, stream>>>(wk, wkt);
  transpose_w<<<tg, tb, 0, stream>>>(wv, wvt);
  transpose_w<<<tg, tb, 0, stream>>>(wo, wot);

  // projections
  dim3 gg(32, 8);
  gemm_bf16<<<gg, 256, 0, stream>>>(qb, wqt, bq, Qh, 0);
  gemm_bf16<<<gg, 256, 0, stream>>>(kb, wkt, bk, Kh, 0);
  gemm_bf16<<<gg, 256, 0, stream>>>(vb, wvt, bv, Vt, 1);

  // attention
  attn_fwd<<<dim3(32, 32), 256, 0, stream>>>(Qh, Kh, Vt, AO);

  // output projection (fp32 out + bias)
  gemm_bf16<<<gg, 256, 0, stream>>>(AO, wot, bo, d_out, 2);
}

// Round 2
// 236.287 us; speedup vs baseline: 1.4946x; 1.4946x over previous
//
#include <hip/hip_runtime.h>
#include <hip/hip_bf16.h>
#include <math.h>

#define DM   1024
#define SEQ  2048
#define NBAT 2
#define NH   16

typedef __attribute__((ext_vector_type(8)))  short short8;
typedef __attribute__((ext_vector_type(4)))  float f32x4;
typedef __attribute__((ext_vector_type(16))) float f32x16;
typedef unsigned short ushort_t;

__device__ __forceinline__ unsigned short f2bf(float f) {
  unsigned int u = __float_as_uint(f);
  u += 0x7fff + ((u >> 16) & 1);   // RNE
  return (unsigned short)(u >> 16);
}

__device__ __forceinline__ unsigned cvtpk(float lo, float hi) {
  unsigned r;
  asm("v_cvt_pk_bf16_f32 %0, %1, %2" : "=v"(r) : "v"(lo), "v"(hi));
  return r;
}

__device__ __forceinline__ short8 mk8(unsigned a, unsigned b, unsigned c, unsigned d) {
  union { unsigned u[4]; short8 s; } x;
  x.u[0] = a; x.u[1] = b; x.u[2] = c; x.u[3] = d;
  return x.s;
}

#define GLDS16(g, l)                                                            \
  __builtin_amdgcn_global_load_lds((const __attribute__((address_space(1))) void*)(g), \
                                   (__attribute__((address_space(3))) void*)(l), 16, 0, 0)

// ---------------- fp32 -> bf16 convert (batched over q,k,v) ------------------
__global__ __launch_bounds__(256) void cvt3(const float* __restrict__ q,
                                            const float* __restrict__ k,
                                            const float* __restrict__ v,
                                            ushort_t* __restrict__ qb,
                                            ushort_t* __restrict__ kb,
                                            ushort_t* __restrict__ vb) {
  int z = blockIdx.y;
  const float* s = z == 0 ? q : z == 1 ? k : v;
  ushort_t* d = z == 0 ? qb : z == 1 ? kb : vb;
  int i = (blockIdx.x * 256 + threadIdx.x) * 8;
  f32x4 a = *(const f32x4*)(s + i);
  f32x4 b = *(const f32x4*)(s + i + 4);
  short8 o;
  o[0] = (short)f2bf(a[0]); o[1] = (short)f2bf(a[1]);
  o[2] = (short)f2bf(a[2]); o[3] = (short)f2bf(a[3]);
  o[4] = (short)f2bf(b[0]); o[5] = (short)f2bf(b[1]);
  o[6] = (short)f2bf(b[2]); o[7] = (short)f2bf(b[3]);
  *(short8*)(d + i) = o;
}

// ---------------- weight transpose + convert (batched over 4 weights) --------
__global__ __launch_bounds__(256) void transpose_w4(
    const float* __restrict__ w0, const float* __restrict__ w1,
    const float* __restrict__ w2, const float* __restrict__ w3,
    ushort_t* __restrict__ o0, ushort_t* __restrict__ o1,
    ushort_t* __restrict__ o2, ushort_t* __restrict__ o3) {
  int z = blockIdx.z;
  const float* W = z == 0 ? w0 : z == 1 ? w1 : z == 2 ? w2 : w3;
  ushort_t* Wt = z == 0 ? o0 : z == 1 ? o1 : z == 2 ? o2 : o3;
  __shared__ float tile[32][33];
  int bx = blockIdx.x * 32;  // n
  int by = blockIdx.y * 32;  // k
  int tx = threadIdx.x, ty = threadIdx.y; // 32 x 8
#pragma unroll
  for (int i = 0; i < 4; ++i)
    tile[ty + i * 8][tx] = W[(size_t)(by + ty + i * 8) * DM + bx + tx];
  __syncthreads();
#pragma unroll
  for (int i = 0; i < 4; ++i)
    Wt[(size_t)(bx + ty + i * 8) * DM + by + tx] = f2bf(tile[tx][ty + i * 8]);
}

// ---------------- QKV projections, z-batched (128x128 tile, m97 structure) ---
// z=0: Q -> bf16 row-major, scaled by 0.125 (folds attn 1/sqrt(d))
// z=1: K -> bf16 row-major
// z=2: V -> Vt[b,h,d,s] transposed bf16
__global__ __launch_bounds__(256) void gemm_qkv(
    const ushort_t* __restrict__ Xq, const ushort_t* __restrict__ Xk, const ushort_t* __restrict__ Xv,
    const ushort_t* __restrict__ Wq, const ushort_t* __restrict__ Wk, const ushort_t* __restrict__ Wv,
    const float* __restrict__ Bq, const float* __restrict__ Bk, const float* __restrict__ Bv,
    ushort_t* __restrict__ Oq, ushort_t* __restrict__ Ok, ushort_t* __restrict__ Ov) {
  const int z = blockIdx.z;
  const ushort_t* X  = z == 0 ? Xq : z == 1 ? Xk : Xv;
  const ushort_t* Wt = z == 0 ? Wq : z == 1 ? Wk : Wv;
  const float* bias  = z == 0 ? Bq : z == 1 ? Bk : Bv;

  __shared__ ushort_t As[128 * 32];
  __shared__ ushort_t Bs[128 * 32];
  const int t = threadIdx.x, l = t & 63, w = t >> 6;
  const int wr = w >> 1, wc = w & 1;
  const int fr = l & 15, fg = l >> 4;
  const int mb = blockIdx.x * 128, nb = blockIdx.y * 128;

  f32x4 acc[4][4] = {};
  const int srow = l >> 2;
  const int scol = (l & 3) * 8;

  for (int kt = 0; kt < DM; kt += 32) {
#pragma unroll
    for (int i = 0; i < 2; ++i) {
      int row = i * 64 + w * 16 + srow;
      GLDS16(X  + (size_t)(mb + row) * DM + kt + scol, &As[i * 2048 + w * 512]);
      GLDS16(Wt + (size_t)(nb + row) * DM + kt + scol, &Bs[i * 2048 + w * 512]);
    }
    __syncthreads();
    short8 af[4], bf[4];
#pragma unroll
    for (int mt = 0; mt < 4; ++mt)
      af[mt] = *(const short8*)&As[(wr * 64 + mt * 16 + fr) * 32 + fg * 8];
#pragma unroll
    for (int nt = 0; nt < 4; ++nt)
      bf[nt] = *(const short8*)&Bs[(wc * 64 + nt * 16 + fr) * 32 + fg * 8];
#pragma unroll
    for (int mt = 0; mt < 4; ++mt)
#pragma unroll
      for (int nt = 0; nt < 4; ++nt)
        acc[mt][nt] = __builtin_amdgcn_mfma_f32_16x16x32_bf16(af[mt], bf[nt], acc[mt][nt], 0, 0, 0);
    __syncthreads();
  }

#pragma unroll
  for (int nt = 0; nt < 4; ++nt) {
    int n = nb + wc * 64 + nt * 16 + fr;
    float bn = bias[n];
#pragma unroll
    for (int mt = 0; mt < 4; ++mt) {
#pragma unroll
      for (int r = 0; r < 4; ++r) {
        int m = mb + wr * 64 + mt * 16 + fg * 4 + r;
        float v = acc[mt][nt][r] + bn;
        if (z == 0) {
          Oq[(size_t)m * DM + n] = f2bf(v * 0.125f);
        } else if (z == 1) {
          Ok[(size_t)m * DM + n] = f2bf(v);
        } else {
          int b = m >> 11, s = m & 2047;
          int h = n >> 6, d = n & 63;
          Ov[(((size_t)(b * NH + h) * 64 + d) * SEQ) + s] = f2bf(v);
        }
      }
    }
  }
}

// ---------------- output projection: 128x64 tile, fp32 out ------------------
__global__ __launch_bounds__(256) void gemm_o(const ushort_t* __restrict__ X,
                                              const ushort_t* __restrict__ Wt,
                                              const float* __restrict__ bias,
                                              float* __restrict__ out) {
  __shared__ ushort_t As[128 * 32];
  __shared__ ushort_t Bs[64 * 32];
  const int t = threadIdx.x, l = t & 63, w = t >> 6;
  const int fr = l & 15, fg = l >> 4;
  const int mb = blockIdx.x * 128, nb = blockIdx.y * 64;

  f32x4 acc[2][4] = {};
  const int srow = l >> 2;
  const int scol = (l & 3) * 8;

  for (int kt = 0; kt < DM; kt += 32) {
#pragma unroll
    for (int i = 0; i < 2; ++i) {
      int row = i * 64 + w * 16 + srow;
      GLDS16(X + (size_t)(mb + row) * DM + kt + scol, &As[i * 2048 + w * 512]);
    }
    GLDS16(Wt + (size_t)(nb + w * 16 + srow) * DM + kt + scol, &Bs[w * 512]);
    __syncthreads();
    short8 af[2], bf[4];
#pragma unroll
    for (int mt = 0; mt < 2; ++mt)
      af[mt] = *(const short8*)&As[(w * 32 + mt * 16 + fr) * 32 + fg * 8];
#pragma unroll
    for (int nt = 0; nt < 4; ++nt)
      bf[nt] = *(const short8*)&Bs[(nt * 16 + fr) * 32 + fg * 8];
#pragma unroll
    for (int mt = 0; mt < 2; ++mt)
#pragma unroll
      for (int nt = 0; nt < 4; ++nt)
        acc[mt][nt] = __builtin_amdgcn_mfma_f32_16x16x32_bf16(af[mt], bf[nt], acc[mt][nt], 0, 0, 0);
    __syncthreads();
  }

#pragma unroll
  for (int nt = 0; nt < 4; ++nt) {
    int n = nb + nt * 16 + fr;
    float bn = bias[n];
#pragma unroll
    for (int mt = 0; mt < 2; ++mt)
#pragma unroll
      for (int r = 0; r < 4; ++r) {
        int m = mb + w * 32 + mt * 16 + fg * 4 + r;
        out[(size_t)m * DM + n] = acc[mt][nt][r] + bn;
      }
  }
}

// ---------------- flash attention: 32x32 MFMA, swapped QK^T -----------------
// Qh (pre-scaled 0.125), Kh: bf16 [NBAT*SEQ][DM]; Vt: bf16 [NBAT*NH][64][SEQ]
// Oh: bf16 [NBAT*SEQ][DM].
// Per block: 4 waves x 32 q-rows = 128 q-rows. KV tile = 64.
#define KPAD 72   // shorts/row: 144 B, 16B-aligned, spreads banks 4-way
__global__ __launch_bounds__(256) void attn_fwd(const ushort_t* __restrict__ Qh,
                                                const ushort_t* __restrict__ Kh,
                                                const ushort_t* __restrict__ Vt,
                                                ushort_t* __restrict__ Oh) {
  __shared__ ushort_t Ks[64 * KPAD];
  __shared__ ushort_t Vs[64 * KPAD];

  const int t = threadIdx.x, l = t & 63, w = t >> 6;
  const int col = l & 31, hi = l >> 5;
  const int q0 = blockIdx.x * 128;
  const int bh = blockIdx.y;
  const int b = bh >> 4, h = bh & 15;

  const ushort_t* Qp = Qh + (size_t)b * SEQ * DM + h * 64;
  const ushort_t* Kp = Kh + (size_t)b * SEQ * DM + h * 64;
  const ushort_t* Vp = Vt + (size_t)bh * 64 * SEQ;

  // Q fragments: Q[qrow][ds*16 + hi*8 + j], held in registers
  const int qrow = q0 + w * 32 + col;
  short8 qf[4];
#pragma unroll
  for (int ds = 0; ds < 4; ++ds)
    qf[ds] = *(const short8*)(Qp + (size_t)qrow * DM + ds * 16 + hi * 8);

  float m_run = -INFINITY, l_run = 0.f;
  f32x16 oA = {}, oB = {};

  const int srow = t >> 3;        // 0..31
  const int scol = (t & 7) * 8;

  // prefetch tile 0 into regs
  short8 k0r = *(const short8*)(Kp + (size_t)srow * DM + scol);
  short8 k1r = *(const short8*)(Kp + (size_t)(32 + srow) * DM + scol);
  short8 v0r = *(const short8*)(Vp + (size_t)srow * SEQ + scol);
  short8 v1r = *(const short8*)(Vp + (size_t)(32 + srow) * SEQ + scol);

  for (int kt = 0; kt < SEQ / 64; ++kt) {
    // write staged regs -> LDS
    *(short8*)&Ks[srow * KPAD + scol] = k0r;
    *(short8*)&Ks[(32 + srow) * KPAD + scol] = k1r;
    *(short8*)&Vs[srow * KPAD + scol] = v0r;
    *(short8*)&Vs[(32 + srow) * KPAD + scol] = v1r;
    __syncthreads();

    // issue next tile's global loads (overlap with compute; last-iter garbage unused)
    {
      int kv = (kt + 1) * 64;
      k0r = *(const short8*)(Kp + (size_t)(kv + srow) * DM + scol);
      k1r = *(const short8*)(Kp + (size_t)(kv + 32 + srow) * DM + scol);
      v0r = *(const short8*)(Vp + (size_t)srow * SEQ + kv + scol);
      v1r = *(const short8*)(Vp + (size_t)(32 + srow) * SEQ + kv + scol);
    }

    // ---- S^T = K_tile @ Q^T (pre-scaled) : two 32-k subtiles ----
    f32x16 s0 = {}, s1 = {};
#pragma unroll
    for (int ds = 0; ds < 4; ++ds) {
      short8 kf0 = *(const short8*)&Ks[col * KPAD + ds * 16 + hi * 8];
      short8 kf1 = *(const short8*)&Ks[(32 + col) * KPAD + ds * 16 + hi * 8];
      s0 = __builtin_amdgcn_mfma_f32_32x32x16_bf16(kf0, qf[ds], s0, 0, 0, 0);
      s1 = __builtin_amdgcn_mfma_f32_32x32x16_bf16(kf1, qf[ds], s1, 0, 0, 0);
    }

    // ---- online softmax (per lane: q = col; 32 of 64 k here, rest in lane^32)
    float mx = s0[0];
#pragma unroll
    for (int r = 1; r < 16; ++r) mx = fmaxf(mx, s0[r]);
#pragma unroll
    for (int r = 0; r < 16; ++r) mx = fmaxf(mx, s1[r]);
    mx = fmaxf(mx, __shfl_xor(mx, 32, 64));

    if (!__all(mx <= m_run + 8.f)) {   // defer-max (T13): rarely taken after tile 0
      float nm = fmaxf(m_run, mx);
      float alpha = __expf(m_run - nm);
      m_run = nm;
      l_run *= alpha;
#pragma unroll
      for (int r = 0; r < 16; ++r) {
        float a = __shfl(alpha, (r & 3) + 8 * (r >> 2) + 4 * hi, 64);
        oA[r] *= a; oB[r] *= a;
      }
    }

    float rs = 0.f;
    float p0[16], p1[16];
#pragma unroll
    for (int r = 0; r < 16; ++r) { p0[r] = __expf(s0[r] - m_run); rs += p0[r]; }
#pragma unroll
    for (int r = 0; r < 16; ++r) { p1[r] = __expf(s1[r] - m_run); rs += p1[r]; }
    rs += __shfl_xor(rs, 32, 64);
    l_run += rs;

    // ---- P -> bf16 pack + half-swap exchange (T12) ----
    unsigned wd[16];
#pragma unroll
    for (int i = 0; i < 8; ++i) wd[i] = cvtpk(p0[2 * i], p0[2 * i + 1]);
#pragma unroll
    for (int i = 0; i < 8; ++i) wd[8 + i] = cvtpk(p1[2 * i], p1[2 * i + 1]);
    unsigned rcv[8];
#pragma unroll
    for (int ksub = 0; ksub < 2; ++ksub) {
      int B = ksub * 8, R = ksub * 4;
      rcv[R + 0] = (unsigned)__shfl_xor((int)(hi ? wd[B + 0] : wd[B + 2]), 32, 64);
      rcv[R + 1] = (unsigned)__shfl_xor((int)(hi ? wd[B + 1] : wd[B + 3]), 32, 64);
      rcv[R + 2] = (unsigned)__shfl_xor((int)(hi ? wd[B + 4] : wd[B + 6]), 32, 64);
      rcv[R + 3] = (unsigned)__shfl_xor((int)(hi ? wd[B + 5] : wd[B + 7]), 32, 64);
    }
    short8 pf[4];
#pragma unroll
    for (int ks = 0; ks < 4; ++ks) {
      int B = (ks >> 1) * 8 + (ks & 1) * 4;
      int R = (ks >> 1) * 4 + (ks & 1) * 2;
      unsigned f0 = hi ? rcv[R]     : wd[B];
      unsigned f1 = hi ? rcv[R + 1] : wd[B + 1];
      unsigned f2 = hi ? wd[B + 2]  : rcv[R];
      unsigned f3 = hi ? wd[B + 3]  : rcv[R + 1];
      pf[ks] = mk8(f0, f1, f2, f3);
    }

    // ---- O += P @ V  (B = V^T rows = Vt layout) ----
#pragma unroll
    for (int ks = 0; ks < 4; ++ks) {
      short8 vfA = *(const short8*)&Vs[col * KPAD + ks * 16 + hi * 8];
      short8 vfB = *(const short8*)&Vs[(32 + col) * KPAD + ks * 16 + hi * 8];
      oA = __builtin_amdgcn_mfma_f32_32x32x16_bf16(pf[ks], vfA, oA, 0, 0, 0);
      oB = __builtin_amdgcn_mfma_f32_32x32x16_bf16(pf[ks], vfB, oB, 0, 0, 0);
    }
    __syncthreads();
  }

  // ---- epilogue: O /= l, write bf16 ----
#pragma unroll
  for (int r = 0; r < 16; ++r) {
    int qr = (r & 3) + 8 * (r >> 2) + 4 * hi;
    float li = __shfl(l_run, qr, 64);
    float inv = __builtin_amdgcn_rcpf(li);
    size_t row = (size_t)(b * SEQ + q0 + w * 32 + qr);
    Oh[row * DM + h * 64 + col]      = f2bf(oA[r] * inv);
    Oh[row * DM + h * 64 + 32 + col] = f2bf(oB[r] * inv);
  }
}

// ---------------------------------------------------------------------------
extern "C" void kernel_launch(void* const* d_in, const int* in_sizes, int n_in,
                              void* d_out, int out_size, void* d_ws, size_t ws_size,
                              hipStream_t stream) {
  const float* v  = (const float*)d_in[0];
  const float* k  = (const float*)d_in[1];
  const float* q  = (const float*)d_in[2];
  const float* wq = (const float*)d_in[3];
  const float* bq = (const float*)d_in[4];
  const float* wk = (const float*)d_in[5];
  const float* bk = (const float*)d_in[6];
  const float* wv = (const float*)d_in[7];
  const float* bv = (const float*)d_in[8];
  const float* wo = (const float*)d_in[9];
  const float* bo = (const float*)d_in[10];

  char* ws = (char*)d_ws;
  const size_t MB = 1u << 20;
  ushort_t* qb  = (ushort_t*)(ws + 0 * MB);
  ushort_t* kb  = (ushort_t*)(ws + 8 * MB);
  ushort_t* vb  = (ushort_t*)(ws + 16 * MB);
  ushort_t* wqt = (ushort_t*)(ws + 24 * MB);
  ushort_t* wkt = (ushort_t*)(ws + 26 * MB);
  ushort_t* wvt = (ushort_t*)(ws + 28 * MB);
  ushort_t* wot = (ushort_t*)(ws + 30 * MB);
  ushort_t* Qh  = (ushort_t*)(ws + 32 * MB);
  ushort_t* Kh  = (ushort_t*)(ws + 40 * MB);
  ushort_t* Vt  = (ushort_t*)(ws + 48 * MB);
  ushort_t* AO  = (ushort_t*)(ws + 56 * MB);

  cvt3<<<dim3(2048, 3), 256, 0, stream>>>(q, k, v, qb, kb, vb);
  transpose_w4<<<dim3(32, 32, 4), dim3(32, 8), 0, stream>>>(wq, wk, wv, wo, wqt, wkt, wvt, wot);
  gemm_qkv<<<dim3(32, 8, 3), 256, 0, stream>>>(qb, kb, vb, wqt, wkt, wvt, bq, bk, bv, Qh, Kh, Vt);
  attn_fwd<<<dim3(16, 32), 256, 0, stream>>>(Qh, Kh, Vt, AO);
  gemm_o<<<dim3(32, 16), 256, 0, stream>>>(AO, wot, bo, (float*)d_out);
}

// Round 3
// 231.248 us; speedup vs baseline: 1.5272x; 1.0218x over previous
//
#include <hip/hip_runtime.h>
#include <hip/hip_bf16.h>
#include <math.h>

#define DM   1024
#define SEQ  2048
#define NBAT 2
#define NH   16

typedef __attribute__((ext_vector_type(8)))  short short8;
typedef __attribute__((ext_vector_type(4)))  float f32x4;
typedef __attribute__((ext_vector_type(16))) float f32x16;
typedef unsigned short ushort_t;

// exp2-domain scale: (1/sqrt(64)) * log2(e)
#define QSCALE 0.1803368801111204f
// defer-max threshold: 8 nats in log2 units
#define DEFER_THR 11.541560327111708f

__device__ __forceinline__ unsigned short f2bf(float f) {
  unsigned int u = __float_as_uint(f);
  u += 0x7fff + ((u >> 16) & 1);   // RNE
  return (unsigned short)(u >> 16);
}

__device__ __forceinline__ unsigned cvtpk(float lo, float hi) {
  unsigned r;
  asm("v_cvt_pk_bf16_f32 %0, %1, %2" : "=v"(r) : "v"(lo), "v"(hi));
  return r;
}

__device__ __forceinline__ short8 mk8(unsigned a, unsigned b, unsigned c, unsigned d) {
  union { unsigned u[4]; short8 s; } x;
  x.u[0] = a; x.u[1] = b; x.u[2] = c; x.u[3] = d;
  return x.s;
}

#define GLDS16(g, l)                                                            \
  __builtin_amdgcn_global_load_lds((const __attribute__((address_space(1))) void*)(g), \
                                   (__attribute__((address_space(3))) void*)(l), 16, 0, 0)

// ---------------- prep: fp32->bf16 convert (z 0..2) + weight transpose (z 3..6)
__global__ __launch_bounds__(256) void prep(
    const float* __restrict__ q, const float* __restrict__ k, const float* __restrict__ v,
    ushort_t* __restrict__ qb, ushort_t* __restrict__ kb, ushort_t* __restrict__ vb,
    const float* __restrict__ w0, const float* __restrict__ w1,
    const float* __restrict__ w2, const float* __restrict__ w3,
    ushort_t* __restrict__ o0, ushort_t* __restrict__ o1,
    ushort_t* __restrict__ o2, ushort_t* __restrict__ o3) {
  const int z = blockIdx.y;
  const int t = threadIdx.x;
  if (z < 3) {
    const float* s = z == 0 ? q : z == 1 ? k : v;
    ushort_t* d = z == 0 ? qb : z == 1 ? kb : vb;
    int i = (blockIdx.x * 256 + t) * 8;
    f32x4 a = *(const f32x4*)(s + i);
    f32x4 b = *(const f32x4*)(s + i + 4);
    short8 o;
    o[0] = (short)f2bf(a[0]); o[1] = (short)f2bf(a[1]);
    o[2] = (short)f2bf(a[2]); o[3] = (short)f2bf(a[3]);
    o[4] = (short)f2bf(b[0]); o[5] = (short)f2bf(b[1]);
    o[6] = (short)f2bf(b[2]); o[7] = (short)f2bf(b[3]);
    *(short8*)(d + i) = o;
  } else {
    if (blockIdx.x >= 1024) return;
    const float* W = z == 3 ? w0 : z == 4 ? w1 : z == 5 ? w2 : w3;
    ushort_t* Wt = z == 3 ? o0 : z == 4 ? o1 : z == 5 ? o2 : o3;
    __shared__ float tile[32][33];
    int bx = (blockIdx.x & 31) * 32;  // n
    int by = (blockIdx.x >> 5) * 32;  // k
    int tx = t & 31, ty = t >> 5;     // 32 x 8
#pragma unroll
    for (int i = 0; i < 4; ++i)
      tile[ty + i * 8][tx] = W[(size_t)(by + ty + i * 8) * DM + bx + tx];
    __syncthreads();
#pragma unroll
    for (int i = 0; i < 4; ++i)
      Wt[(size_t)(bx + ty + i * 8) * DM + by + tx] = f2bf(tile[tx][ty + i * 8]);
  }
}

// ---------------- QKV projections, z-batched (128x128 tile, BK=64, swizzled) -
// z=0: Q -> bf16 row-major, scaled by QSCALE (folds 1/sqrt(d) * log2e)
// z=1: K -> bf16 row-major
// z=2: V -> Vt[b,h,d,s] transposed bf16
__global__ __launch_bounds__(256) void gemm_qkv(
    const ushort_t* __restrict__ Xq, const ushort_t* __restrict__ Xk, const ushort_t* __restrict__ Xv,
    const ushort_t* __restrict__ Wq, const ushort_t* __restrict__ Wk, const ushort_t* __restrict__ Wv,
    const float* __restrict__ Bq, const float* __restrict__ Bk, const float* __restrict__ Bv,
    ushort_t* __restrict__ Oq, ushort_t* __restrict__ Ok, ushort_t* __restrict__ Ov) {
  const int z = blockIdx.z;
  const ushort_t* X  = z == 0 ? Xq : z == 1 ? Xk : Xv;
  const ushort_t* Wt = z == 0 ? Wq : z == 1 ? Wk : Wv;
  const float* bias  = z == 0 ? Bq : z == 1 ? Bk : Bv;

  __shared__ ushort_t As[128 * 64];   // 16 KB
  __shared__ ushort_t Bs[128 * 64];   // 16 KB
  const int t = threadIdx.x, l = t & 63, w = t >> 6;
  const int wr = w >> 1, wc = w & 1;
  const int fr = l & 15, fg = l >> 4;
  const int mb = blockIdx.x * 128, nb = blockIdx.y * 128;

  f32x4 acc[4][4] = {};
  // staging: lane l covers LDS row (i*32 + w*8 + l>>3), chunk l&7 (of 8B).
  // pre-swizzled global source: chunk c at LDS row r holds global chunk c^(r&7)
  const int srow = w * 8 + (l >> 3);
  const int gcol = (((l & 7) ^ ((l >> 3) & 7))) * 8;

  for (int kt = 0; kt < DM; kt += 64) {
#pragma unroll
    for (int i = 0; i < 4; ++i) {
      int row = i * 32 + srow;
      GLDS16(X  + (size_t)(mb + row) * DM + kt + gcol, &As[i * 2048 + w * 512]);
      GLDS16(Wt + (size_t)(nb + row) * DM + kt + gcol, &Bs[i * 2048 + w * 512]);
    }
    __syncthreads();
#pragma unroll
    for (int ks = 0; ks < 2; ++ks) {
      short8 af[4], bf[4];
#pragma unroll
      for (int mt = 0; mt < 4; ++mt) {
        int row = wr * 64 + mt * 16 + fr;
        af[mt] = *(const short8*)&As[row * 64 + (((ks << 2) | fg) ^ (fr & 7)) * 8];
      }
#pragma unroll
      for (int nt = 0; nt < 4; ++nt) {
        int row = wc * 64 + nt * 16 + fr;
        bf[nt] = *(const short8*)&Bs[row * 64 + (((ks << 2) | fg) ^ (fr & 7)) * 8];
      }
#pragma unroll
      for (int mt = 0; mt < 4; ++mt)
#pragma unroll
        for (int nt = 0; nt < 4; ++nt)
          acc[mt][nt] = __builtin_amdgcn_mfma_f32_16x16x32_bf16(af[mt], bf[nt], acc[mt][nt], 0, 0, 0);
    }
    __syncthreads();
  }

#pragma unroll
  for (int nt = 0; nt < 4; ++nt) {
    int n = nb + wc * 64 + nt * 16 + fr;
    float bn = bias[n];
#pragma unroll
    for (int mt = 0; mt < 4; ++mt) {
#pragma unroll
      for (int r = 0; r < 4; ++r) {
        int m = mb + wr * 64 + mt * 16 + fg * 4 + r;
        float v = acc[mt][nt][r] + bn;
        if (z == 0) {
          Oq[(size_t)m * DM + n] = f2bf(v * QSCALE);
        } else if (z == 1) {
          Ok[(size_t)m * DM + n] = f2bf(v);
        } else {
          int b = m >> 11, s = m & 2047;
          int h = n >> 6, d = n & 63;
          Ov[(((size_t)(b * NH + h) * 64 + d) * SEQ) + s] = f2bf(v);
        }
      }
    }
  }
}

// ---------------- output projection: 128x64 tile, BK=64, fp32 out -----------
__global__ __launch_bounds__(256) void gemm_o(const ushort_t* __restrict__ X,
                                              const ushort_t* __restrict__ Wt,
                                              const float* __restrict__ bias,
                                              float* __restrict__ out) {
  __shared__ ushort_t As[128 * 64];   // 16 KB
  __shared__ ushort_t Bs[64 * 64];    // 8 KB
  const int t = threadIdx.x, l = t & 63, w = t >> 6;
  const int fr = l & 15, fg = l >> 4;
  const int mb = blockIdx.x * 128, nb = blockIdx.y * 64;

  f32x4 acc[2][4] = {};
  const int srow = w * 8 + (l >> 3);
  const int gcol = (((l & 7) ^ ((l >> 3) & 7))) * 8;

  for (int kt = 0; kt < DM; kt += 64) {
#pragma unroll
    for (int i = 0; i < 4; ++i)
      GLDS16(X + (size_t)(mb + i * 32 + srow) * DM + kt + gcol, &As[i * 2048 + w * 512]);
#pragma unroll
    for (int i = 0; i < 2; ++i)
      GLDS16(Wt + (size_t)(nb + i * 32 + srow) * DM + kt + gcol, &Bs[i * 2048 + w * 512]);
    __syncthreads();
#pragma unroll
    for (int ks = 0; ks < 2; ++ks) {
      short8 af[2], bf[4];
#pragma unroll
      for (int mt = 0; mt < 2; ++mt) {
        int row = w * 32 + mt * 16 + fr;
        af[mt] = *(const short8*)&As[row * 64 + (((ks << 2) | fg) ^ (fr & 7)) * 8];
      }
#pragma unroll
      for (int nt = 0; nt < 4; ++nt) {
        int row = nt * 16 + fr;
        bf[nt] = *(const short8*)&Bs[row * 64 + (((ks << 2) | fg) ^ (fr & 7)) * 8];
      }
#pragma unroll
      for (int mt = 0; mt < 2; ++mt)
#pragma unroll
        for (int nt = 0; nt < 4; ++nt)
          acc[mt][nt] = __builtin_amdgcn_mfma_f32_16x16x32_bf16(af[mt], bf[nt], acc[mt][nt], 0, 0, 0);
    }
    __syncthreads();
  }

#pragma unroll
  for (int nt = 0; nt < 4; ++nt) {
    int n = nb + nt * 16 + fr;
    float bn = bias[n];
#pragma unroll
    for (int mt = 0; mt < 2; ++mt)
#pragma unroll
      for (int r = 0; r < 4; ++r) {
        int m = mb + w * 32 + mt * 16 + fg * 4 + r;
        out[(size_t)m * DM + n] = acc[mt][nt][r] + bn;
      }
  }
}

// ---------------- flash attention: 32x32 MFMA, swapped QK^T, dbuf LDS -------
// Qh (pre-scaled QSCALE), Kh: bf16 [NBAT*SEQ][DM]; Vt: bf16 [NBAT*NH][64][SEQ]
// Oh: bf16 [NBAT*SEQ][DM].  Softmax in exp2 domain.
#define KPAD 72
#define KVELEM (64 * KPAD)
__global__ __launch_bounds__(256) void attn_fwd(const ushort_t* __restrict__ Qh,
                                                const ushort_t* __restrict__ Kh,
                                                const ushort_t* __restrict__ Vt,
                                                ushort_t* __restrict__ Oh) {
  __shared__ ushort_t Ks[2 * KVELEM];
  __shared__ ushort_t Vs[2 * KVELEM];

  const int t = threadIdx.x, l = t & 63, w = t >> 6;
  const int col = l & 31, hi = l >> 5;
  const int q0 = blockIdx.x * 128;
  const int bh = blockIdx.y;
  const int b = bh >> 4, h = bh & 15;

  const ushort_t* Qp = Qh + (size_t)b * SEQ * DM + h * 64;
  const ushort_t* Kp = Kh + (size_t)b * SEQ * DM + h * 64;
  const ushort_t* Vp = Vt + (size_t)bh * 64 * SEQ;

  const int qrow = q0 + w * 32 + col;
  short8 qf[4];
#pragma unroll
  for (int ds = 0; ds < 4; ++ds)
    qf[ds] = *(const short8*)(Qp + (size_t)qrow * DM + ds * 16 + hi * 8);

  float m_run = -INFINITY, l_run = 0.f;
  f32x16 oA = {}, oB = {};

  const int srow = t >> 3;        // 0..31
  const int scol = (t & 7) * 8;

  // prologue: tile0 -> regs -> LDS[0]; issue tile1 -> regs
  short8 k0r = *(const short8*)(Kp + (size_t)srow * DM + scol);
  short8 k1r = *(const short8*)(Kp + (size_t)(32 + srow) * DM + scol);
  short8 v0r = *(const short8*)(Vp + (size_t)srow * SEQ + scol);
  short8 v1r = *(const short8*)(Vp + (size_t)(32 + srow) * SEQ + scol);
  *(short8*)&Ks[srow * KPAD + scol] = k0r;
  *(short8*)&Ks[(32 + srow) * KPAD + scol] = k1r;
  *(short8*)&Vs[srow * KPAD + scol] = v0r;
  *(short8*)&Vs[(32 + srow) * KPAD + scol] = v1r;
  k0r = *(const short8*)(Kp + (size_t)(64 + srow) * DM + scol);
  k1r = *(const short8*)(Kp + (size_t)(96 + srow) * DM + scol);
  v0r = *(const short8*)(Vp + (size_t)srow * SEQ + 64 + scol);
  v1r = *(const short8*)(Vp + (size_t)(32 + srow) * SEQ + 64 + scol);
  __syncthreads();

  const int NT = SEQ / 64;
  for (int kt = 0; kt < NT; ++kt) {
    const ushort_t* Kc = &Ks[(kt & 1) * KVELEM];
    const ushort_t* Vc = &Vs[(kt & 1) * KVELEM];

    // ---- S^T = K_tile @ Q^T (pre-scaled, log2 units) ----
    f32x16 s0 = {}, s1 = {};
    __builtin_amdgcn_s_setprio(1);
#pragma unroll
    for (int ds = 0; ds < 4; ++ds) {
      short8 kf0 = *(const short8*)&Kc[col * KPAD + ds * 16 + hi * 8];
      short8 kf1 = *(const short8*)&Kc[(32 + col) * KPAD + ds * 16 + hi * 8];
      s0 = __builtin_amdgcn_mfma_f32_32x32x16_bf16(kf0, qf[ds], s0, 0, 0, 0);
      s1 = __builtin_amdgcn_mfma_f32_32x32x16_bf16(kf1, qf[ds], s1, 0, 0, 0);
    }
    __builtin_amdgcn_s_setprio(0);

    // ---- online softmax (exp2 domain) ----
    float mx = s0[0];
#pragma unroll
    for (int r = 1; r < 16; ++r) mx = fmaxf(mx, s0[r]);
#pragma unroll
    for (int r = 0; r < 16; ++r) mx = fmaxf(mx, s1[r]);
    mx = fmaxf(mx, __shfl_xor(mx, 32, 64));

    if (!__all(mx <= m_run + DEFER_THR)) {   // defer-max: rarely taken after tile 0
      float nm = fmaxf(m_run, mx);
      float alpha = __builtin_amdgcn_exp2f(m_run - nm);
      m_run = nm;
      l_run *= alpha;
#pragma unroll
      for (int r = 0; r < 16; ++r) {
        float a = __shfl(alpha, (r & 3) + 8 * (r >> 2) + 4 * hi, 64);
        oA[r] *= a; oB[r] *= a;
      }
    }

    float rs = 0.f;
    float p0[16], p1[16];
#pragma unroll
    for (int r = 0; r < 16; ++r) { p0[r] = __builtin_amdgcn_exp2f(s0[r] - m_run); rs += p0[r]; }
#pragma unroll
    for (int r = 0; r < 16; ++r) { p1[r] = __builtin_amdgcn_exp2f(s1[r] - m_run); rs += p1[r]; }
    rs += __shfl_xor(rs, 32, 64);
    l_run += rs;

    // ---- P -> bf16 pack + half-swap exchange ----
    unsigned wd[16];
#pragma unroll
    for (int i = 0; i < 8; ++i) wd[i] = cvtpk(p0[2 * i], p0[2 * i + 1]);
#pragma unroll
    for (int i = 0; i < 8; ++i) wd[8 + i] = cvtpk(p1[2 * i], p1[2 * i + 1]);
    unsigned rcv[8];
#pragma unroll
    for (int ksub = 0; ksub < 2; ++ksub) {
      int B = ksub * 8, R = ksub * 4;
      rcv[R + 0] = (unsigned)__shfl_xor((int)(hi ? wd[B + 0] : wd[B + 2]), 32, 64);
      rcv[R + 1] = (unsigned)__shfl_xor((int)(hi ? wd[B + 1] : wd[B + 3]), 32, 64);
      rcv[R + 2] = (unsigned)__shfl_xor((int)(hi ? wd[B + 4] : wd[B + 6]), 32, 64);
      rcv[R + 3] = (unsigned)__shfl_xor((int)(hi ? wd[B + 5] : wd[B + 7]), 32, 64);
    }
    short8 pf[4];
#pragma unroll
    for (int ks = 0; ks < 4; ++ks) {
      int B = (ks >> 1) * 8 + (ks & 1) * 4;
      int R = (ks >> 1) * 4 + (ks & 1) * 2;
      unsigned f0 = hi ? rcv[R]     : wd[B];
      unsigned f1 = hi ? rcv[R + 1] : wd[B + 1];
      unsigned f2 = hi ? wd[B + 2]  : rcv[R];
      unsigned f3 = hi ? wd[B + 3]  : rcv[R + 1];
      pf[ks] = mk8(f0, f1, f2, f3);
    }

    // ---- O += P @ V ----
    __builtin_amdgcn_s_setprio(1);
#pragma unroll
    for (int ks = 0; ks < 4; ++ks) {
      short8 vfA = *(const short8*)&Vc[col * KPAD + ks * 16 + hi * 8];
      short8 vfB = *(const short8*)&Vc[(32 + col) * KPAD + ks * 16 + hi * 8];
      oA = __builtin_amdgcn_mfma_f32_32x32x16_bf16(pf[ks], vfA, oA, 0, 0, 0);
      oB = __builtin_amdgcn_mfma_f32_32x32x16_bf16(pf[ks], vfB, oB, 0, 0, 0);
    }
    __builtin_amdgcn_s_setprio(0);

    // ---- write-late staged tile kt+1, issue loads tile kt+2 ----
    if (kt + 1 < NT) {
      ushort_t* Kn = &Ks[((kt + 1) & 1) * KVELEM];
      ushort_t* Vn = &Vs[((kt + 1) & 1) * KVELEM];
      *(short8*)&Kn[srow * KPAD + scol] = k0r;
      *(short8*)&Kn[(32 + srow) * KPAD + scol] = k1r;
      *(short8*)&Vn[srow * KPAD + scol] = v0r;
      *(short8*)&Vn[(32 + srow) * KPAD + scol] = v1r;
      int kv2 = (kt + 2 < NT) ? (kt + 2) * 64 : 0;
      k0r = *(const short8*)(Kp + (size_t)(kv2 + srow) * DM + scol);
      k1r = *(const short8*)(Kp + (size_t)(kv2 + 32 + srow) * DM + scol);
      v0r = *(const short8*)(Vp + (size_t)srow * SEQ + kv2 + scol);
      v1r = *(const short8*)(Vp + (size_t)(32 + srow) * SEQ + kv2 + scol);
      __syncthreads();
    }
  }

  // ---- epilogue: O /= l, write bf16 ----
#pragma unroll
  for (int r = 0; r < 16; ++r) {
    int qr = (r & 3) + 8 * (r >> 2) + 4 * hi;
    float li = __shfl(l_run, qr, 64);
    float inv = __builtin_amdgcn_rcpf(li);
    size_t row = (size_t)(b * SEQ + q0 + w * 32 + qr);
    Oh[row * DM + h * 64 + col]      = f2bf(oA[r] * inv);
    Oh[row * DM + h * 64 + 32 + col] = f2bf(oB[r] * inv);
  }
}

// ---------------------------------------------------------------------------
extern "C" void kernel_launch(void* const* d_in, const int* in_sizes, int n_in,
                              void* d_out, int out_size, void* d_ws, size_t ws_size,
                              hipStream_t stream) {
  const float* v  = (const float*)d_in[0];
  const float* k  = (const float*)d_in[1];
  const float* q  = (const float*)d_in[2];
  const float* wq = (const float*)d_in[3];
  const float* bq = (const float*)d_in[4];
  const float* wk = (const float*)d_in[5];
  const float* bk = (const float*)d_in[6];
  const float* wv = (const float*)d_in[7];
  const float* bv = (const float*)d_in[8];
  const float* wo = (const float*)d_in[9];
  const float* bo = (const float*)d_in[10];

  char* ws = (char*)d_ws;
  const size_t MB = 1u << 20;
  ushort_t* qb  = (ushort_t*)(ws + 0 * MB);
  ushort_t* kb  = (ushort_t*)(ws + 8 * MB);
  ushort_t* vb  = (ushort_t*)(ws + 16 * MB);
  ushort_t* wqt = (ushort_t*)(ws + 24 * MB);
  ushort_t* wkt = (ushort_t*)(ws + 26 * MB);
  ushort_t* wvt = (ushort_t*)(ws + 28 * MB);
  ushort_t* wot = (ushort_t*)(ws + 30 * MB);
  ushort_t* Qh  = (ushort_t*)(ws + 32 * MB);
  ushort_t* Kh  = (ushort_t*)(ws + 40 * MB);
  ushort_t* Vt  = (ushort_t*)(ws + 48 * MB);
  ushort_t* AO  = (ushort_t*)(ws + 56 * MB);

  prep<<<dim3(2048, 7), 256, 0, stream>>>(q, k, v, qb, kb, vb,
                                          wq, wk, wv, wo, wqt, wkt, wvt, wot);
  gemm_qkv<<<dim3(32, 8, 3), 256, 0, stream>>>(qb, kb, vb, wqt, wkt, wvt, bq, bk, bv, Qh, Kh, Vt);
  attn_fwd<<<dim3(16, 32), 256, 0, stream>>>(Qh, Kh, Vt, AO);
  gemm_o<<<dim3(32, 16), 256, 0, stream>>>(AO, wot, bo, (float*)d_out);
}